// Round 7
// baseline (493.036 us; speedup 1.0000x reference)
//
#include <hip/hip_runtime.h>
#include <hip/hip_bf16.h>
#include <stdint.h>

// Problem constants
#define NN   1000000      // NUM_NODES
#define DD   128          // MEM_DIM == MSG_DIM
#define BT   262144       // batch B
#define TR   32           // rows per LDS tile (2 MFMA sub-tiles)
#define RPB  512          // batch rows per GRU block
#define NT   (RPB / TR)   // 16 tiles per block
#define GRUB (BT / RPB)   // 512 GRU blocks
#define WINBIT (1 << 30)

typedef __attribute__((ext_vector_type(8))) short bf16x8;  // 8 bf16 in 4 VGPRs
typedef __attribute__((ext_vector_type(4))) float f32x4;

// float pair -> packed bf16x2 via v_cvt_pk_bf16_f32 (compiler-emitted)
__device__ __forceinline__ uint32_t f2bf2(float lo, float hi) {
    __hip_bfloat162 b = __float22bfloat162_rn(make_float2(lo, hi));
    uint32_t u; __builtin_memcpy(&u, &b, 4); return u;
}
__device__ __forceinline__ bf16x8 cvt8(float4 a, float4 b) {
    union { bf16x8 v; uint32_t u[4]; } r;
    r.u[0] = f2bf2(a.x, a.y);
    r.u[1] = f2bf2(a.z, a.w);
    r.u[2] = f2bf2(b.x, b.y);
    r.u[3] = f2bf2(b.z, b.w);
    return r.v;
}
__device__ __forceinline__ bf16x8 cvt8v(f32x4 a, f32x4 b) {
    union { bf16x8 v; uint32_t u[4]; } r;
    r.u[0] = f2bf2(a[0], a[1]);
    r.u[1] = f2bf2(a[2], a[3]);
    r.u[2] = f2bf2(b[0], b[1]);
    r.u[3] = f2bf2(b[2], b[3]);
    return r.v;
}
__device__ __forceinline__ float fastrcp(float x) {
    return __builtin_amdgcn_rcpf(x);
}
__device__ __forceinline__ float sigmoid_f(float x) {
    return fastrcp(1.0f + __expf(-x));
}
__device__ __forceinline__ float tanh_f(float x) {
    return fmaf(2.0f, fastrcp(1.0f + __expf(-2.0f * x)), -1.0f);
}
// async global->LDS, 16B per lane; lds dest must be wave-uniform base
__device__ __forceinline__ void glds16(const float* g, void* l) {
    __builtin_amdgcn_global_load_lds(
        (const __attribute__((address_space(1))) uint32_t*)g,
        (__attribute__((address_space(3))) uint32_t*)l, 16, 0, 0);
}

// ---------------------------------------------------------------------------
// winner[] = -1
__global__ __launch_bounds__(256) void k_init(int4* __restrict__ winner) {
    int i = blockIdx.x * 256 + threadIdx.x;
    if (i < NN / 4) winner[i] = make_int4(-1, -1, -1, -1);
}

// last-occurrence-wins winner per node
__global__ __launch_bounds__(256) void k_winner(const int* __restrict__ node_ids,
                                                int* __restrict__ winner) {
    int i = blockIdx.x * 256 + threadIdx.x;
    if (i < BT) atomicMax(&winner[node_ids[i]], i);
}

// ---------------------------------------------------------------------------
// copy memory rows not owned by a winner; write last_update for all nodes.
__global__ __launch_bounds__(256) void k_copy(const float4* __restrict__ mem_in,
                                              const float* __restrict__ lu_in,
                                              const float* __restrict__ ts,
                                              const int* __restrict__ winner,
                                              float4* __restrict__ mem_out,
                                              float* __restrict__ lu_out) {
    const long NV4 = (long)NN * 32;        // 32 float4 per row
    const long TOTAL = NV4 + NN;
    long stride = (long)gridDim.x * 256;
    for (long i = blockIdx.x * 256L + threadIdx.x; i < TOTAL; i += stride) {
        if (i < NV4) {
            int node = (int)(i >> 5);
            if (winner[node] < 0) mem_out[i] = mem_in[i];
        } else {
            int v = (int)(i - NV4);
            int w = winner[v];
            lu_out[v] = (w >= 0) ? ts[w] : lu_in[v];
        }
    }
}

// ---------------------------------------------------------------------------
// Fused gather + GRU (bf16 MFMA) + gated scatter.
// 512 thr = 8 waves; wave w owns output cols [16w,16w+16), all 24 weight
// B-fragments register-resident. 16 tiles of 32 rows staged f32 into
// double-buffered LDS via global_load_lds (linear LDS, XOR-swizzle applied by
// permuting the per-lane GLOBAL source col-chunk). Pipeline depth 2 tiles,
// counted s_waitcnt vmcnt(4) (never drains the younger tile's loads).
// Two raw s_barriers per tile: B (buf ready) ... compute ... B' (buf free),
// then issue glds for tile t+2 into the just-freed buffer.
// mfma_f32_16x16x32_bf16: A[r][k]: r=lane&15, k=8*(lane>>4)+e
//                         B[k][n]: n=lane&15, same k
//                         D[r][c]: c=lane&15, r=4*(lane>>4)+q
__global__ __launch_bounds__(512, 4) void k_gru(const float* __restrict__ memory,
                                                const float* __restrict__ messages,
                                                const float* __restrict__ W_ih,
                                                const float* __restrict__ W_hh,
                                                const float* __restrict__ b_ih,
                                                const float* __restrict__ b_hh,
                                                const int* __restrict__ node_ids,
                                                const int* __restrict__ winner,
                                                float* __restrict__ out_mem) {
    __shared__ float x_lds[2][TR * DD];   // 2 x 16 KB, f32, source-swizzled
    __shared__ float h_lds[2][TR * DD];   // 2 x 16 KB, f32, source-swizzled
    __shared__ int s_nid[RPB];            // nid | (win << 30)

    const int tid = threadIdx.x;
    const int rowBase = blockIdx.x * RPB;

    for (int i = tid; i < RPB; i += 512) {
        int brow = rowBase + i;
        int nid = node_ids[brow];
        s_nid[i] = nid | ((winner[nid] == brow) ? WINBIT : 0);
    }
    __syncthreads();

    const int lane  = tid & 63;
    const int wave  = tid >> 6;
    const int l15   = lane & 15;
    const int khalf = lane >> 4;            // 0..3
    const int jcol  = wave * 16 + l15;      // this lane's output column

    // weight fragments (fp32 -> bf16 via cvt_pk), register-resident
    bf16x8 wf[6][4];
#pragma unroll
    for (int g = 0; g < 3; ++g) {
#pragma unroll
        for (int ks = 0; ks < 4; ++ks) {
            const float* p = W_ih + (size_t)(g * 128 + jcol) * DD + ks * 32 + khalf * 8;
            wf[g][ks] = cvt8(*(const float4*)p, *(const float4*)(p + 4));
            const float* q = W_hh + (size_t)(g * 128 + jcol) * DD + ks * 32 + khalf * 8;
            wf[3 + g][ks] = cvt8(*(const float4*)q, *(const float4*)(q + 4));
        }
    }
    // biases folded into accumulator init
    const float br  = b_ih[jcol] + b_hh[jcol];
    const float bz  = b_ih[128 + jcol] + b_hh[128 + jcol];
    const float bin = b_ih[256 + jcol];
    const float bhn = b_hh[256 + jcol];

    // glds staging geometry: per array 2 instrs; instr i covers 16B chunk
    // (tid + i*512) of the 1024-chunk [32][128] f32 tile.
    // lane row = chunk>>5, col-chunk cc = chunk&31; SOURCE col-chunk is
    // cc ^ (row&7)  -> LDS linear layout equals the XOR-swizzled layout.
    const int lrow0 = tid >> 5;               // 0..15 (instr0); instr1 = +16
    const int scc   = (tid & 31) ^ (lrow0 & 7);  // (lrow0+16)&7 == lrow0&7
    const int ldsw0 = wave * 1024;            // wave-uniform byte offsets
    const int ldsw1 = wave * 1024 + 8192;

#define STAGE(t, b)                                                              \
    {                                                                            \
        const int r0_ = (t) * TR + lrow0;                                        \
        const float* xs0_ = messages + (size_t)(rowBase + r0_) * DD + scc * 4;   \
        const float* xs1_ = messages + (size_t)(rowBase + r0_ + 16) * DD + scc * 4; \
        const float* hs0_ = memory + (size_t)(s_nid[r0_] & (WINBIT - 1)) * DD + scc * 4; \
        const float* hs1_ = memory + (size_t)(s_nid[r0_ + 16] & (WINBIT - 1)) * DD + scc * 4; \
        glds16(xs0_, (char*)(&x_lds[b][0]) + ldsw0);                             \
        glds16(xs1_, (char*)(&x_lds[b][0]) + ldsw1);                             \
        glds16(hs0_, (char*)(&h_lds[b][0]) + ldsw0);                             \
        glds16(hs1_, (char*)(&h_lds[b][0]) + ldsw1);                             \
    }

    // prologue: 2 tiles in flight (8 glds outstanding)
    STAGE(0, 0);
    STAGE(1, 1);

#pragma unroll 1
    for (int t = 0; t < NT; ++t) {
        const int buf = t & 1;
        // wait for tile t's 4 glds; leave tile t+1's 4 in flight.
        // (older epilogue stores retire in-order before these glds.)
        if (t + 1 < NT) { asm volatile("s_waitcnt vmcnt(4)" ::: "memory"); }
        else            { asm volatile("s_waitcnt vmcnt(0)" ::: "memory"); }
        __builtin_amdgcn_sched_barrier(0);
        __builtin_amdgcn_s_barrier();           // B: buf ready for all waves
        __builtin_amdgcn_sched_barrier(0);

        // compute: two 16-row sub-tiles
#pragma unroll
        for (int sub = 0; sub < 2; ++sub) {
            const int arow = sub * 16 + l15;
            const char* xb = (const char*)(&x_lds[buf][0]) + arow * 512;
            const char* hb = (const char*)(&h_lds[buf][0]) + arow * 512;
            const int as = arow & 7;
            f32x4 a_r  = {br,  br,  br,  br};
            f32x4 a_z  = {bz,  bz,  bz,  bz};
            f32x4 a_in = {bin, bin, bin, bin};
            f32x4 a_hn = {bhn, bhn, bhn, bhn};
#pragma unroll
            for (int ks = 0; ks < 4; ++ks) {
                const int c0 = ks * 8 + khalf * 2;
                f32x4 x0 = *(const f32x4*)(xb + ((c0 ^ as) * 16));
                f32x4 x1 = *(const f32x4*)(xb + (((c0 + 1) ^ as) * 16));
                f32x4 h0 = *(const f32x4*)(hb + ((c0 ^ as) * 16));
                f32x4 h1 = *(const f32x4*)(hb + (((c0 + 1) ^ as) * 16));
                bf16x8 axk = cvt8v(x0, x1);
                bf16x8 ahk = cvt8v(h0, h1);
                a_r  = __builtin_amdgcn_mfma_f32_16x16x32_bf16(axk, wf[0][ks], a_r,  0, 0, 0);
                a_r  = __builtin_amdgcn_mfma_f32_16x16x32_bf16(ahk, wf[3][ks], a_r,  0, 0, 0);
                a_z  = __builtin_amdgcn_mfma_f32_16x16x32_bf16(axk, wf[1][ks], a_z,  0, 0, 0);
                a_z  = __builtin_amdgcn_mfma_f32_16x16x32_bf16(ahk, wf[4][ks], a_z,  0, 0, 0);
                a_in = __builtin_amdgcn_mfma_f32_16x16x32_bf16(axk, wf[2][ks], a_in, 0, 0, 0);
                a_hn = __builtin_amdgcn_mfma_f32_16x16x32_bf16(ahk, wf[5][ks], a_hn, 0, 0, 0);
            }
#pragma unroll
            for (int q = 0; q < 4; ++q) {
                const int rl = sub * 16 + khalf * 4 + q;   // row within tile
                const int tr = t * TR + rl;                // row within block
                float rg = sigmoid_f(a_r[q]);
                float zg = sigmoid_f(a_z[q]);
                float ng = tanh_f(a_in[q] + rg * a_hn[q]);
                // epilogue h: full f32 from LDS (source-swizzled layout)
                float h = h_lds[buf][rl * 128 + (((jcol >> 2) ^ (rl & 7)) * 4) + (jcol & 3)];
                float hnew = fmaf(zg, h - ng, ng);         // (1-z)n + zh
                int v = s_nid[tr];
                if (v & WINBIT)
                    out_mem[(size_t)(v & (WINBIT - 1)) * DD + jcol] = hnew;
            }
        }

        __builtin_amdgcn_sched_barrier(0);
        __builtin_amdgcn_s_barrier();           // B': all waves done with buf
        __builtin_amdgcn_sched_barrier(0);
        if (t + 2 < NT) STAGE(t + 2, buf);      // refill freed buffer
    }
#undef STAGE
}

// ---------------------------------------------------------------------------
extern "C" void kernel_launch(void* const* d_in, const int* in_sizes, int n_in,
                              void* d_out, int out_size, void* d_ws, size_t ws_size,
                              hipStream_t stream) {
    const float* memory      = (const float*)d_in[0];
    const float* last_update = (const float*)d_in[1];
    const float* messages    = (const float*)d_in[2];
    const float* timestamps  = (const float*)d_in[3];
    const float* W_ih        = (const float*)d_in[4];
    const float* W_hh        = (const float*)d_in[5];
    const float* b_ih        = (const float*)d_in[6];
    const float* b_hh        = (const float*)d_in[7];
    const int*   node_ids    = (const int*)d_in[8];

    float* out_mem = (float*)d_out;
    float* out_lu  = out_mem + (size_t)NN * DD;

    int* winner = (int*)d_ws;

    k_init<<<(NN / 4 + 255) / 256, 256, 0, stream>>>((int4*)winner);
    k_winner<<<BT / 256, 256, 0, stream>>>(node_ids, winner);
    k_copy<<<4096, 256, 0, stream>>>((const float4*)memory, last_update, timestamps,
                                     winner, (float4*)out_mem, out_lu);
    k_gru<<<GRUB, 512, 0, stream>>>(memory, messages, W_ih, W_hh, b_ih, b_hh,
                                    node_ids, winner, out_mem);
}

// Round 8
// 462.193 us; speedup vs baseline: 1.0667x; 1.0667x over previous
//
#include <hip/hip_runtime.h>
#include <hip/hip_bf16.h>
#include <stdint.h>

// Problem constants
#define NN   1000000      // NUM_NODES
#define DD   128          // MEM_DIM == MSG_DIM
#define BT   262144       // batch B
#define TR   64           // rows per LDS tile (4 MFMA sub-tiles)
#define RPB  512          // batch rows per GRU block
#define NT   (RPB / TR)   // 8 tiles per block
#define GRUB (BT / RPB)   // 512 GRU blocks
#define WINBIT (1 << 30)
#define NV4  32000000L    // float4 elements in memory buffer (NN*32)

typedef __attribute__((ext_vector_type(8))) short bf16x8;  // 8 bf16 in 4 VGPRs
typedef __attribute__((ext_vector_type(4))) float f32x4;

// float pair -> packed bf16x2 via v_cvt_pk_bf16_f32 (compiler-emitted)
__device__ __forceinline__ uint32_t f2bf2(float lo, float hi) {
    __hip_bfloat162 b = __float22bfloat162_rn(make_float2(lo, hi));
    uint32_t u; __builtin_memcpy(&u, &b, 4); return u;
}
__device__ __forceinline__ bf16x8 cvt8(float4 a, float4 b) {
    union { bf16x8 v; uint32_t u[4]; } r;
    r.u[0] = f2bf2(a.x, a.y);
    r.u[1] = f2bf2(a.z, a.w);
    r.u[2] = f2bf2(b.x, b.y);
    r.u[3] = f2bf2(b.z, b.w);
    return r.v;
}
__device__ __forceinline__ float bf2f(unsigned short s) {
    union { uint32_t u; float f; } c; c.u = ((uint32_t)s) << 16;
    return c.f;
}
__device__ __forceinline__ float fastrcp(float x) {
    return __builtin_amdgcn_rcpf(x);
}
__device__ __forceinline__ float sigmoid_f(float x) {
    return fastrcp(1.0f + __expf(-x));
}
__device__ __forceinline__ float tanh_f(float x) {
    return fmaf(2.0f, fastrcp(1.0f + __expf(-2.0f * x)), -1.0f);
}

// ---------------------------------------------------------------------------
// winner[] = -1
__global__ __launch_bounds__(256) void k_init(int4* __restrict__ winner) {
    int i = blockIdx.x * 256 + threadIdx.x;
    if (i < NN / 4) winner[i] = make_int4(-1, -1, -1, -1);
}

// last-occurrence-wins winner per node
__global__ __launch_bounds__(256) void k_winner(const int* __restrict__ node_ids,
                                                int* __restrict__ winner) {
    int i = blockIdx.x * 256 + threadIdx.x;
    if (i < BT) atomicMax(&winner[node_ids[i]], i);
}

// ---------------------------------------------------------------------------
// Fused gather + GRU (bf16 MFMA) + gated scatter + INTERLEAVED stream-copy.
// 512 thr = 8 waves; wave w owns output cols [16w,16w+16), all 24 weight
// B-fragments register-resident. 8 tiles of 64 rows, double-buffered
// XOR-swizzled bf16 LDS, one lgkm-barrier per tile, register prefetch in
// flight across it. After each tile's epilogue (accumulators dead), the block
// copies one grid-coalesced 8192-float4 chunk of memory->out (winner-gated):
// the copy's streaming loads/stores fill the GRU's gather-latency bubbles,
// fusing the BW-bound copy with the latency-bound GRU on every CU.
// mfma_f32_16x16x32_bf16: A[r][k]: r=lane&15, k=8*(lane>>4)+e
//                         B[k][n]: n=lane&15, same k
//                         D[r][c]: c=lane&15, r=4*(lane>>4)+q
__global__ __launch_bounds__(512, 2) void k_gru(const float* __restrict__ memory,
                                                const float* __restrict__ messages,
                                                const float* __restrict__ W_ih,
                                                const float* __restrict__ W_hh,
                                                const float* __restrict__ b_ih,
                                                const float* __restrict__ b_hh,
                                                const int* __restrict__ node_ids,
                                                const int* __restrict__ winner,
                                                const float* __restrict__ lu_in,
                                                const float* __restrict__ ts,
                                                float* __restrict__ out_mem,
                                                float* __restrict__ out_lu) {
    __shared__ unsigned short x_lds[2][TR * DD];   // 2 x 16 KB, swizzled
    __shared__ unsigned short h_lds[2][TR * DD];   // 2 x 16 KB, swizzled
    __shared__ int s_nid[RPB];                     // nid | (win << 30)

    const int tid = threadIdx.x;
    const int rowBase = blockIdx.x * RPB;

    for (int i = tid; i < RPB; i += 512) {
        int brow = rowBase + i;
        int nid = node_ids[brow];
        s_nid[i] = nid | ((winner[nid] == brow) ? WINBIT : 0);
    }
    __syncthreads();

    const int lane  = tid & 63;
    const int wave  = tid >> 6;
    const int l15   = lane & 15;
    const int khalf = lane >> 4;            // 0..3
    const int jcol  = wave * 16 + l15;      // this lane's output column

    // weight fragments (fp32 -> bf16 via cvt_pk), register-resident
    bf16x8 wf[6][4];
#pragma unroll
    for (int g = 0; g < 3; ++g) {
#pragma unroll
        for (int ks = 0; ks < 4; ++ks) {
            const float* p = W_ih + (size_t)(g * 128 + jcol) * DD + ks * 32 + khalf * 8;
            wf[g][ks] = cvt8(*(const float4*)p, *(const float4*)(p + 4));
            const float* q = W_hh + (size_t)(g * 128 + jcol) * DD + ks * 32 + khalf * 8;
            wf[3 + g][ks] = cvt8(*(const float4*)q, *(const float4*)(q + 4));
        }
    }
    // biases folded into accumulator init
    const float br  = b_ih[jcol] + b_hh[jcol];
    const float bz  = b_ih[128 + jcol] + b_hh[128 + jcol];
    const float bin = b_ih[256 + jcol];
    const float bhn = b_hh[256 + jcol];

    // staging geometry: half-tile of 32 rows; thread -> (row sr, 8-col sc8)
    const int sr  = tid >> 4;               // 0..31
    const int sc8 = (tid & 15) * 8;         // 0..120
    const int swz = (sc8 * 2) ^ ((sr & 7) << 4);
    const int offH0 = sr * 256 + swz;
    const int offH1 = (32 + sr) * 256 + swz;

    const float4* mem4 = (const float4*)memory;
    float4* out4 = (float4*)out_mem;

#define GLOAD(X0, X1, H0, H1, t, half)                                          \
    {                                                                           \
        int r_ = (t) * TR + (half) * 32 + sr;                                   \
        const float* xp_ = messages + (size_t)(rowBase + r_) * DD + sc8;        \
        X0 = ((const float4*)xp_)[0]; X1 = ((const float4*)xp_)[1];             \
        const float* hp_ = memory + (size_t)(s_nid[r_] & (WINBIT - 1)) * DD + sc8; \
        H0 = ((const float4*)hp_)[0]; H1 = ((const float4*)hp_)[1];             \
    }

    // prefetch tile 0 (both halves): 8 float4 in flight per thread
    float4 xA0, xA1, hA0, hA1, xB0, xB1, hB0, hB1;
    GLOAD(xA0, xA1, hA0, hA1, 0, 0);
    GLOAD(xB0, xB1, hB0, hB1, 0, 1);

#pragma unroll 1
    for (int t = 0; t < NT; ++t) {
        const int buf = t & 1;
        char* xb = (char*)(&x_lds[buf][0]);
        char* hb = (char*)(&h_lds[buf][0]);
        *(bf16x8*)(xb + offH0) = cvt8(xA0, xA1);
        *(bf16x8*)(hb + offH0) = cvt8(hA0, hA1);
        *(bf16x8*)(xb + offH1) = cvt8(xB0, xB1);
        *(bf16x8*)(hb + offH1) = cvt8(hB0, hB1);
        if (t + 1 < NT) {
            GLOAD(xA0, xA1, hA0, hA1, t + 1, 0);
            GLOAD(xB0, xB1, hB0, hB1, t + 1, 1);
        }
        // LDS-visible barrier that does NOT drain vmcnt
        asm volatile("s_waitcnt lgkmcnt(0)" ::: "memory");
        __builtin_amdgcn_sched_barrier(0);
        __builtin_amdgcn_s_barrier();
        __builtin_amdgcn_sched_barrier(0);

        // compute: four 16-row sub-tiles
#pragma unroll
        for (int sub = 0; sub < 4; ++sub) {
            const int arow = sub * 16 + l15;
            const char* xr = (const char*)(&x_lds[buf][0]) + arow * 256;
            const char* hr = (const char*)(&h_lds[buf][0]) + arow * 256;
            const int aswz = (arow & 7) << 4;
            bf16x8 ax[4], ah[4];
#pragma unroll
            for (int ks = 0; ks < 4; ++ks) {
                const int cb = (ks * 64 + khalf * 16) ^ aswz;
                ax[ks] = *(const bf16x8*)(xr + cb);
                ah[ks] = *(const bf16x8*)(hr + cb);
            }
            f32x4 a_r  = {br,  br,  br,  br};
            f32x4 a_z  = {bz,  bz,  bz,  bz};
            f32x4 a_in = {bin, bin, bin, bin};
            f32x4 a_hn = {bhn, bhn, bhn, bhn};
#pragma unroll
            for (int ks = 0; ks < 4; ++ks) {
                a_r  = __builtin_amdgcn_mfma_f32_16x16x32_bf16(ax[ks], wf[0][ks], a_r,  0, 0, 0);
                a_r  = __builtin_amdgcn_mfma_f32_16x16x32_bf16(ah[ks], wf[3][ks], a_r,  0, 0, 0);
                a_z  = __builtin_amdgcn_mfma_f32_16x16x32_bf16(ax[ks], wf[1][ks], a_z,  0, 0, 0);
                a_z  = __builtin_amdgcn_mfma_f32_16x16x32_bf16(ah[ks], wf[4][ks], a_z,  0, 0, 0);
                a_in = __builtin_amdgcn_mfma_f32_16x16x32_bf16(ax[ks], wf[2][ks], a_in, 0, 0, 0);
                a_hn = __builtin_amdgcn_mfma_f32_16x16x32_bf16(ah[ks], wf[5][ks], a_hn, 0, 0, 0);
            }
#pragma unroll
            for (int q = 0; q < 4; ++q) {
                const int rl = sub * 16 + khalf * 4 + q;   // row within tile
                const int tr = t * TR + rl;                // row within block
                float rg = sigmoid_f(a_r[q]);
                float zg = sigmoid_f(a_z[q]);
                float ng = tanh_f(a_in[q] + rg * a_hn[q]);
                unsigned short hu = *(const unsigned short*)(
                    (const char*)(&h_lds[buf][0]) + rl * 256 + ((jcol * 2) ^ ((rl & 7) << 4)));
                float h = bf2f(hu);
                float hnew = fmaf(zg, h - ng, ng);         // (1-z)n + zh
                int v = s_nid[tr];
                if (v & WINBIT)
                    out_mem[(size_t)(v & (WINBIT - 1)) * DD + jcol] = hnew;
            }
        }

        // ---- interleaved copy chunk (accumulators dead -> regs free):
        // 8192 float4, grid-coalesced, winner-gated last-update-safe copy.
        {
            const long base4 = ((long)(blockIdx.x * NT + t)) * 8192 + tid;
#pragma unroll
            for (int k = 0; k < 16; ++k) {
                long f = base4 + (long)k * 512;
                if (f < NV4 && winner[(int)(f >> 5)] < 0) out4[f] = mem4[f];
            }
        }
    }
#undef GLOAD

    // ---- last_update slice ----
    for (int i = blockIdx.x * 512 + tid; i < NN; i += GRUB * 512) {
        int w = winner[i];
        out_lu[i] = (w >= 0) ? ts[w] : lu_in[i];
    }
}

// ---------------------------------------------------------------------------
extern "C" void kernel_launch(void* const* d_in, const int* in_sizes, int n_in,
                              void* d_out, int out_size, void* d_ws, size_t ws_size,
                              hipStream_t stream) {
    const float* memory      = (const float*)d_in[0];
    const float* last_update = (const float*)d_in[1];
    const float* messages    = (const float*)d_in[2];
    const float* timestamps  = (const float*)d_in[3];
    const float* W_ih        = (const float*)d_in[4];
    const float* W_hh        = (const float*)d_in[5];
    const float* b_ih        = (const float*)d_in[6];
    const float* b_hh        = (const float*)d_in[7];
    const int*   node_ids    = (const int*)d_in[8];

    float* out_mem = (float*)d_out;
    float* out_lu  = out_mem + (size_t)NN * DD;

    int* winner = (int*)d_ws;

    k_init<<<(NN / 4 + 255) / 256, 256, 0, stream>>>((int4*)winner);
    k_winner<<<BT / 256, 256, 0, stream>>>(node_ids, winner);
    k_gru<<<GRUB, 512, 0, stream>>>(memory, messages, W_ih, W_hh, b_ih, b_hh,
                                    node_ids, winner, last_update, timestamps,
                                    out_mem, out_lu);
}